// Round 3
// baseline (133.792 us; speedup 1.0000x reference)
//
#include <hip/hip_runtime.h>
#include <hip/hip_bf16.h>

#define Bsz 4
#define Lsz 2048
#define Hsz 8

typedef __attribute__((ext_vector_type(8)))  short bf16x8;
typedef __attribute__((ext_vector_type(4)))  float f32x4;
typedef __attribute__((ext_vector_type(16))) float f32x16;
typedef __attribute__((ext_vector_type(2)))  unsigned u32x2;

__device__ __forceinline__ short f2bs(float f) {   // RNE
    union { float f; unsigned u; } v; v.f = f;
    unsigned r = v.u + 0x7FFFu + ((v.u >> 16) & 1u);
    return (short)(r >> 16);
}
__device__ __forceinline__ unsigned cvtpk(float lo, float hi) {
    unsigned r;
    asm("v_cvt_pk_bf16_f32 %0, %1, %2" : "=v"(r) : "v"(lo), "v"(hi));
    return r;
}

// async global->LDS, 16B per lane; LDS dest is wave-uniform base + lane*16
__device__ __forceinline__ void stage16(const short* g, short* l) {
    __builtin_amdgcn_global_load_lds(
        (const __attribute__((address_space(1))) unsigned int*)g,
        (__attribute__((address_space(3))) unsigned int*)l,
        16, 0, 0);
}

// ---------------- pre-pass: K and V -> bf16 32x32x16 MFMA fragments ----------------
// Per (bh, 64-key tile): 8 chunks x 1024 B each for K and V. NEW: both K and V are
// kh-major so a wave's half-tile is one contiguous 4 KB block:
// K chunk c = kh*4 + eb          lane(l31,hi): K[kh*32+l31][eb*16+hi*8+j]
// V chunk c = kh*4 + dh*2 + kbl  lane(l31,hi): V[kh*32+kbl*16+hi*8+j][dh*32+l31] (V^T)
__global__ __launch_bounds__(256) void prep_kv(
    const float* __restrict__ ksrc, const float* __restrict__ vsrc,
    short* __restrict__ Kf, short* __restrict__ Vf)
{
    __shared__ float Tl[64][65];
    const int raw = blockIdx.x;
    const int tid = threadIdx.x;
    const bool isK = raw < Bsz*Hsz*32;
    const int bid = isK ? raw : raw - Bsz*Hsz*32;
    const int tl = bid & 31, bh = bid >> 5;
    const int b = bh >> 3, h = bh & 7;

    const int row = tid >> 2, c0 = (tid & 3) * 16;
    const float* src = (isK ? ksrc : vsrc)
                     + (((size_t)b*Lsz + tl*64 + row)*Hsz + h)*64 + c0;
    *(float4*)&Tl[row][c0]      = *(const float4*)(src);
    *(float4*)&Tl[row][c0 + 4]  = *(const float4*)(src + 4);
    *(float4*)&Tl[row][c0 + 8]  = *(const float4*)(src + 8);
    *(float4*)&Tl[row][c0 + 12] = *(const float4*)(src + 12);
    __syncthreads();

    const int lane = tid & 63, l31 = lane & 31, hi = lane >> 5;
    if (isK) {
        short* dst = Kf + (size_t)bid * 4096;
        #pragma unroll
        for (int cc = 0; cc < 2; ++cc) {
            const int c  = (tid >> 6)*2 + cc;      // 0..7
            const int kh = c >> 2, eb = c & 3;
            const float* rp = &Tl[kh*32 + l31][eb*16 + hi*8];
            bf16x8 o = {f2bs(rp[0]),f2bs(rp[1]),f2bs(rp[2]),f2bs(rp[3]),
                        f2bs(rp[4]),f2bs(rp[5]),f2bs(rp[6]),f2bs(rp[7])};
            *(bf16x8*)(dst + c*512 + lane*8) = o;
        }
    } else {
        short* dst = Vf + (size_t)bid * 4096;
        #pragma unroll
        for (int cc = 0; cc < 2; ++cc) {
            const int c  = (tid >> 6)*2 + cc;      // logical (dh,kb)
            const int dh = c >> 2, kb = c & 3;
            const int cp = (kb >> 1)*4 + dh*2 + (kb & 1);   // kh-major physical chunk
            const int d  = dh*32 + l31;
            const int s0 = kb*16 + hi*8;
            bf16x8 o = {f2bs(Tl[s0+0][d]), f2bs(Tl[s0+1][d]),
                        f2bs(Tl[s0+2][d]), f2bs(Tl[s0+3][d]),
                        f2bs(Tl[s0+4][d]), f2bs(Tl[s0+5][d]),
                        f2bs(Tl[s0+6][d]), f2bs(Tl[s0+7][d])};
            *(bf16x8*)(dst + cp*512 + lane*8) = o;
        }
    }
}

// ---------------- main: barrier-free per-wave pipeline (counted vmcnt) ----------
// 128 thr = 2 waves; wave kh owns keys kh*32..+32 of each tile x ALL 64 queries.
// Each wave stages ONLY its own 8 KB (K-half + V-half) into a PRIVATE LDS dbuf ->
// zero __syncthreads in the main loop; per-wave s_waitcnt vmcnt(N) (never 0 while
// streaming) overlaps tile t+1 loads with tile t compute. 40 KB LDS -> 4 blocks/CU.
__global__ __launch_bounds__(128, 2) void dsattn_main(
    const float* __restrict__ q,
    const short* __restrict__ Kf,
    const short* __restrict__ Vf,
    const float* __restrict__ tau,
    const float* __restrict__ delta,
    float* __restrict__ out)
{
    __shared__ __align__(16) short Wb[2][2][4096]; // [wave][dbuf][4KB K | 4KB V]
    __shared__ float dls[Lsz];                     //  8 KB c2*delta[b][:]
    // total 40 KB -> 4 blocks/CU (8 waves/CU, 2/SIMD)

    const int tid  = threadIdx.x;
    const int kh   = tid >> 6;        // wave id == key-half
    const int lane = tid & 63;
    const int l31  = lane & 31;
    const int hi   = lane >> 5;

    const int bh = blockIdx.x;
    const int b  = bh >> 3, h = bh & 7;
    // co-resident {y, y+8, y+16, y+24} -> qt {31-2a, 2a, 30-2a, 2a+1}: 66 tiles/CU
    const int y = blockIdx.y, g8 = y >> 3, a = y & 7;
    const int qt = (g8 == 0) ? 31 - 2*a : (g8 == 1) ? 2*a
                 : (g8 == 2) ? 30 - 2*a : 2*a + 1;
    const int q0 = qt * 64;
    const int T  = qt + 1;            // 64-key tiles

    const float c2  = 0.125f * 1.44269504f;   // scale * log2(e)
    const float st2 = c2 * tau[b];

    const short* gK = Kf + (size_t)bh*(32*4096) + kh*2048 + lane*8;
    const short* gV = Vf + (size_t)bh*(32*4096) + kh*2048 + lane*8;
    short* const myb = &Wb[kh][0][0];

    // stage this wave's half of one tile (4 K-chunks then 4 V-chunks), advance ptrs
#define STAGE(buf) do {                                                     \
        short* lb_ = myb + (buf)*4096;                                      \
        stage16(gK + 0*512, lb_ + 0*512);                                   \
        stage16(gK + 1*512, lb_ + 1*512);                                   \
        stage16(gK + 2*512, lb_ + 2*512);                                   \
        stage16(gK + 3*512, lb_ + 3*512);                                   \
        stage16(gV + 0*512, lb_ + 2048 + 0*512);                            \
        stage16(gV + 1*512, lb_ + 2048 + 1*512);                            \
        stage16(gV + 2*512, lb_ + 2048 + 2*512);                            \
        stage16(gV + 3*512, lb_ + 2048 + 3*512);                            \
        gK += 4096; gV += 4096;                                             \
        __builtin_amdgcn_sched_barrier(0);                                  \
    } while (0)

    // counted vmcnt wait, fenced (rule #18: memory clobber + sched_barrier)
#define WAITN(n) do {                                                       \
        asm volatile("s_waitcnt vmcnt(" #n ")" ::: "memory");               \
        __builtin_amdgcn_sched_barrier(0);                                  \
    } while (0)

    STAGE(0);                         // tile 0 in flight first

    // stage c2*delta (128 thr x 16 floats)
    {
        const float* dsrc = delta + (size_t)b*Lsz + tid*16;
        #pragma unroll
        for (int u = 0; u < 4; ++u) {
            float4 v = *(const float4*)(dsrc + u*4);
            v.x*=c2; v.y*=c2; v.z*=c2; v.w*=c2;
            *(float4*)&dls[tid*16 + u*4] = v;
        }
    }

    // Q fragments for BOTH q-halves (each wave computes all 64 queries)
    bf16x8 qf[4][2];
    #pragma unroll
    for (int qh = 0; qh < 2; ++qh) {
        const float* qrow = q + (((size_t)b*Lsz + q0 + qh*32 + l31)*Hsz + h)*64 + hi*8;
        #pragma unroll
        for (int eb = 0; eb < 4; ++eb) {
            float4 a0 = *(const float4*)(qrow + eb*16);
            float4 a1 = *(const float4*)(qrow + eb*16 + 4);
            qf[eb][qh] = (bf16x8){f2bs(a0.x),f2bs(a0.y),f2bs(a0.z),f2bs(a0.w),
                                  f2bs(a1.x),f2bs(a1.y),f2bs(a1.z),f2bs(a1.w)};
        }
    }

    f32x16 oacc[2][2];                // [dh][qh]
    #pragma unroll
    for (int dh = 0; dh < 2; ++dh)
        #pragma unroll
        for (int qh = 0; qh < 2; ++qh)
            #pragma unroll
            for (int i = 0; i < 16; ++i) oacc[dh][qh][i] = 0.f;
    float l_a0 = 0.f, l_a1 = 0.f;

    __syncthreads();                  // tile 0 + dls staged; vmcnt drained (once)

#define TILE_BODY(t_, MASKED, HASNEXT) do {                                 \
        const short* cb_ = myb + ((t_) & 1)*4096;                           \
        const int k0_ = (t_)*64;                                            \
        if (HASNEXT) STAGE(((t_)+1) & 1);                                   \
        if (HASNEXT) WAITN(12); else WAITN(4);     /* K(t) resident */      \
        f32x16 s0_, s1_;                                                    \
        _Pragma("unroll")                                                   \
        for (int i = 0; i < 16; ++i) { s0_[i] = 0.f; s1_[i] = 0.f; }        \
        __builtin_amdgcn_s_setprio(1);                                      \
        _Pragma("unroll")                                                   \
        for (int eb = 0; eb < 4; ++eb) {                                    \
            bf16x8 kf_ = *(const bf16x8*)(cb_ + eb*512 + lane*8);           \
            s0_ = __builtin_amdgcn_mfma_f32_32x32x16_bf16(kf_, qf[eb][0], s0_, 0,0,0); \
            s1_ = __builtin_amdgcn_mfma_f32_32x32x16_bf16(kf_, qf[eb][1], s1_, 0,0,0); \
        }                                                                   \
        __builtin_amdgcn_s_setprio(0);                                      \
        if (MASKED) {                                                       \
            _Pragma("unroll")                                               \
            for (int g = 0; g < 4; ++g)                                     \
                _Pragma("unroll")                                           \
                for (int i = 0; i < 4; ++i) {                               \
                    const int ky_ = kh*32 + 8*g + 4*hi + i;                 \
                    if (ky_ >      l31) s0_[g*4+i] = -1e30f;                \
                    if (ky_ > 32 + l31) s1_[g*4+i] = -1e30f;                \
                }                                                           \
        }                                                                   \
        float p0_[16], p1_[16];                                             \
        _Pragma("unroll")                                                   \
        for (int g = 0; g < 4; ++g) {                                       \
            f32x4 dlv_ = *(const f32x4*)&dls[k0_ + kh*32 + g*8 + hi*4];     \
            _Pragma("unroll")                                               \
            for (int i = 0; i < 4; ++i) {                                   \
                p0_[g*4+i] = __builtin_amdgcn_exp2f(fmaf(s0_[g*4+i], st2, dlv_[i])); \
                p1_[g*4+i] = __builtin_amdgcn_exp2f(fmaf(s1_[g*4+i], st2, dlv_[i])); \
            }                                                               \
            l_a0 += (p0_[g*4]+p0_[g*4+1]) + (p0_[g*4+2]+p0_[g*4+3]);        \
            l_a1 += (p1_[g*4]+p1_[g*4+1]) + (p1_[g*4+2]+p1_[g*4+3]);        \
        }                                                                   \
        bf16x8 pf0_[2], pf1_[2];                                            \
        _Pragma("unroll")                                                   \
        for (int kb = 0; kb < 2; ++kb) {                                    \
            unsigned a0_ = cvtpk(p0_[kb*8+0], p0_[kb*8+1]);                 \
            unsigned a1_ = cvtpk(p0_[kb*8+2], p0_[kb*8+3]);                 \
            unsigned b0_ = cvtpk(p0_[kb*8+4], p0_[kb*8+5]);                 \
            unsigned b1_ = cvtpk(p0_[kb*8+6], p0_[kb*8+7]);                 \
            u32x2 s0s_ = __builtin_amdgcn_permlane32_swap(a0_, b0_, false, false); \
            u32x2 s1s_ = __builtin_amdgcn_permlane32_swap(a1_, b1_, false, false); \
            union { unsigned u[4]; bf16x8 v; } pk_;                         \
            pk_.u[0] = s0s_[0]; pk_.u[1] = s1s_[0];                         \
            pk_.u[2] = s0s_[1]; pk_.u[3] = s1s_[1];                         \
            pf0_[kb] = pk_.v;                                               \
            unsigned c0_ = cvtpk(p1_[kb*8+0], p1_[kb*8+1]);                 \
            unsigned c1_ = cvtpk(p1_[kb*8+2], p1_[kb*8+3]);                 \
            unsigned d0_ = cvtpk(p1_[kb*8+4], p1_[kb*8+5]);                 \
            unsigned d1_ = cvtpk(p1_[kb*8+6], p1_[kb*8+7]);                 \
            u32x2 s2s_ = __builtin_amdgcn_permlane32_swap(c0_, d0_, false, false); \
            u32x2 s3s_ = __builtin_amdgcn_permlane32_swap(c1_, d1_, false, false); \
            union { unsigned u[4]; bf16x8 v; } pk2_;                        \
            pk2_.u[0] = s2s_[0]; pk2_.u[1] = s3s_[0];                       \
            pk2_.u[2] = s2s_[1]; pk2_.u[3] = s3s_[1];                       \
            pf1_[kb] = pk2_.v;                                              \
        }                                                                   \
        if (HASNEXT) WAITN(8); else WAITN(0);      /* V(t) resident */      \
        __builtin_amdgcn_s_setprio(1);                                      \
        _Pragma("unroll")                                                   \
        for (int kb = 0; kb < 2; ++kb)                                      \
            _Pragma("unroll")                                               \
            for (int dh = 0; dh < 2; ++dh) {                                \
                bf16x8 vf_ = *(const bf16x8*)(cb_ + 2048 + (dh*2+kb)*512 + lane*8); \
                oacc[dh][0] = __builtin_amdgcn_mfma_f32_32x32x16_bf16(vf_, pf0_[kb], oacc[dh][0], 0,0,0); \
                oacc[dh][1] = __builtin_amdgcn_mfma_f32_32x32x16_bf16(vf_, pf1_[kb], oacc[dh][1], 0,0,0); \
            }                                                               \
        __builtin_amdgcn_s_setprio(0);                                      \
    } while (0)

    // barrier-free main loop; diagonal (masked) tile last, no staging
    for (int t = 0; t < T - 1; ++t) TILE_BODY(t, false, true);
    TILE_BODY(T - 1, true, false);

    // ---- cross-wave (kh) reduction via LDS, then normalize + store ----
    float lw0 = l_a0 + __shfl_xor(l_a0, 32, 64);
    float lw1 = l_a1 + __shfl_xor(l_a1, 32, 64);
    float* Ored = (float*)&Wb[0][0][0];   // 4096 f32 = 16 KB
    float* lred = Ored + 4096;            // 64 f32
    __syncthreads();                      // all tile reads of Wb done

    if (kh == 1) {
        #pragma unroll
        for (int qh = 0; qh < 2; ++qh)
            #pragma unroll
            for (int dh = 0; dh < 2; ++dh)
                #pragma unroll
                for (int g = 0; g < 4; ++g)
                    #pragma unroll
                    for (int i = 0; i < 4; ++i) {
                        const int d_ = dh*32 + 8*g + 4*hi + i;
                        Ored[(qh*64 + d_)*32 + l31] = oacc[dh][qh][g*4+i];
                    }
        if (lane < 32) { lred[l31] = lw0; lred[32 + l31] = lw1; }
    }
    __syncthreads();

    if (kh == 0) {
        #pragma unroll
        for (int qh = 0; qh < 2; ++qh) {
            const float lw = (qh == 0) ? lw0 : lw1;
            const float invl = 1.0f / (lw + lred[qh*32 + l31]);
            float* orow = out + (((size_t)b*Lsz + q0 + qh*32 + l31)*Hsz + h)*64;
            #pragma unroll
            for (int dh = 0; dh < 2; ++dh)
                #pragma unroll
                for (int g = 0; g < 4; ++g) {
                    const int d_ = dh*32 + 8*g + 4*hi;
                    float4 o;
                    o.x = (oacc[dh][qh][g*4+0] + Ored[(qh*64 + d_ + 0)*32 + l31]) * invl;
                    o.y = (oacc[dh][qh][g*4+1] + Ored[(qh*64 + d_ + 1)*32 + l31]) * invl;
                    o.z = (oacc[dh][qh][g*4+2] + Ored[(qh*64 + d_ + 2)*32 + l31]) * invl;
                    o.w = (oacc[dh][qh][g*4+3] + Ored[(qh*64 + d_ + 3)*32 + l31]) * invl;
                    *(float4*)(orow + d_) = o;
                }
        }
    }
#undef STAGE
#undef WAITN
#undef TILE_BODY
}

extern "C" void kernel_launch(void* const* d_in, const int* in_sizes, int n_in,
                              void* d_out, int out_size, void* d_ws, size_t ws_size,
                              hipStream_t stream) {
    (void)in_sizes; (void)n_in; (void)out_size; (void)ws_size;
    const float* q     = (const float*)d_in[0];
    const float* k     = (const float*)d_in[1];
    const float* v     = (const float*)d_in[2];
    const float* tau   = (const float*)d_in[3];
    const float* delta = (const float*)d_in[4];
    float* out = (float*)d_out;

    short* Kf = (short*)d_ws;                          // 8 MiB bf16 fragments
    short* Vf = (short*)d_ws + (size_t)(4*1024*1024);  // next 8 MiB

    prep_kv<<<dim3(Bsz*Hsz*32*2), dim3(256), 0, stream>>>(k, v, Kf, Vf);
    dsattn_main<<<dim3(Bsz*Hsz, 32), dim3(128), 0, stream>>>(q, Kf, Vf, tau, delta, out);
}

// Round 4
// 129.569 us; speedup vs baseline: 1.0326x; 1.0326x over previous
//
#include <hip/hip_runtime.h>
#include <hip/hip_bf16.h>

#define Bsz 4
#define Lsz 2048
#define Hsz 8

typedef __attribute__((ext_vector_type(8)))  short bf16x8;
typedef __attribute__((ext_vector_type(4)))  short bf16x4;
typedef __attribute__((ext_vector_type(4)))  float f32x4;

__device__ __forceinline__ short f2bs(float f) {   // RNE
    union { float f; unsigned u; } v; v.f = f;
    unsigned r = v.u + 0x7FFFu + ((v.u >> 16) & 1u);
    return (short)(r >> 16);
}
__device__ __forceinline__ short f2bs_rh(float f) { // round-half-up, 2 ops
    return (short)((__float_as_uint(f) + 0x8000u) >> 16);
}

// async global->LDS, 16B per lane; LDS dest is wave-uniform base + lane*16
__device__ __forceinline__ void stage16(const short* g, short* l) {
    __builtin_amdgcn_global_load_lds(
        (const __attribute__((address_space(1))) unsigned int*)g,
        (__attribute__((address_space(3))) unsigned int*)l,
        16, 0, 0);
}

// ---------------- pre-pass: K, V -> bf16 fragments (kq-major), Df = c2*delta ----
// Per (bh, 64-key tile), 8 chunks x 1 KB each, kq = key-16-block owner wave:
// K chunk c = kq*2+eb:   lane(ln,quad): K[kq*16+ln][eb*32+quad*8+j]   (A 16x16x32)
// V chunk c = kq*2+dgp:  lane 16B = [frag(dg=2dgp) | frag(dg=2dgp+1)], each
//    frag 8B = V[kq*16+quad*4+j][dg*16+ln], j=0..3                    (A 16x16x16)
__global__ __launch_bounds__(256) void prep_kv(
    const float* __restrict__ ksrc, const float* __restrict__ vsrc,
    const float* __restrict__ delta,
    short* __restrict__ Kf, short* __restrict__ Vf, float* __restrict__ Df)
{
    const int raw = blockIdx.x;
    const int tid = threadIdx.x;
    if (raw >= 2*Bsz*Hsz*32) {         // Df: c2 * delta, 2 blocks x 256 thr x 16 f
        const float c2 = 0.125f * 1.44269504f;
        const int base = ((raw - 2*Bsz*Hsz*32)*256 + tid) * 16;
        #pragma unroll
        for (int u = 0; u < 4; ++u) {
            float4 v = *(const float4*)(delta + base + u*4);
            v.x*=c2; v.y*=c2; v.z*=c2; v.w*=c2;
            *(float4*)(Df + base + u*4) = v;
        }
        return;
    }
    __shared__ float Tl[64][65];
    const bool isK = raw < Bsz*Hsz*32;
    const int bid = isK ? raw : raw - Bsz*Hsz*32;
    const int tl = bid & 31, bh = bid >> 5;
    const int b = bh >> 3, h = bh & 7;

    const int row = tid >> 2, c0 = (tid & 3) * 16;
    const float* src = (isK ? ksrc : vsrc)
                     + (((size_t)b*Lsz + tl*64 + row)*Hsz + h)*64 + c0;
    *(float4*)&Tl[row][c0]      = *(const float4*)(src);
    *(float4*)&Tl[row][c0 + 4]  = *(const float4*)(src + 4);
    *(float4*)&Tl[row][c0 + 8]  = *(const float4*)(src + 8);
    *(float4*)&Tl[row][c0 + 12] = *(const float4*)(src + 12);
    __syncthreads();

    const int lane = tid & 63, ln = lane & 15, quad = lane >> 4;
    if (isK) {
        short* dst = Kf + (size_t)bid * 4096;
        #pragma unroll
        for (int cc = 0; cc < 2; ++cc) {
            const int c  = (tid >> 6)*2 + cc;      // 0..7 = kq*2+eb
            const int kq = c >> 1, eb = c & 1;
            const float* rp = &Tl[kq*16 + ln][eb*32 + quad*8];
            bf16x8 o = {f2bs(rp[0]),f2bs(rp[1]),f2bs(rp[2]),f2bs(rp[3]),
                        f2bs(rp[4]),f2bs(rp[5]),f2bs(rp[6]),f2bs(rp[7])};
            *(bf16x8*)(dst + c*512 + lane*8) = o;
        }
    } else {
        short* dst = Vf + (size_t)bid * 4096;
        #pragma unroll
        for (int cc = 0; cc < 2; ++cc) {
            const int c   = (tid >> 6)*2 + cc;     // 0..7 = kq*2+dgp
            const int kq  = c >> 1, dgp = c & 1;
            const int s0  = kq*16 + quad*4;
            const int d0  = dgp*32 + ln;           // dg=2dgp
            const int d1  = dgp*32 + 16 + ln;      // dg=2dgp+1
            bf16x8 o = {f2bs(Tl[s0+0][d0]), f2bs(Tl[s0+1][d0]),
                        f2bs(Tl[s0+2][d0]), f2bs(Tl[s0+3][d0]),
                        f2bs(Tl[s0+0][d1]), f2bs(Tl[s0+1][d1]),
                        f2bs(Tl[s0+2][d1]), f2bs(Tl[s0+3][d1])};
            *(bf16x8*)(dst + c*512 + lane*8) = o;
        }
    }
}

// ---------------- main: barrier-free, 4 independent wave-pipelines per block ----
// 256 thr = 4 waves; wave kq owns keys kq*16..+16 of every tile x ALL 64 queries.
// Each wave stages only ITS 4 KB slice (2 KB K + 2 KB V) into its private dbuf
// region -> zero cross-wave LDS deps in the loop -> NO __syncthreads in the loop.
// Counted per-wave s_waitcnt vmcnt(8/5) (never drained while streaming).
// Q (8 KB bf16 frags) in LDS, read-only after one prologue barrier.
// 40 KB LDS -> 4 blocks/CU = 16 waves/CU.
__global__ __launch_bounds__(256, 4) void dsattn_main(
    const float* __restrict__ q,
    const short* __restrict__ Kf,
    const short* __restrict__ Vf,
    const float* __restrict__ Df,
    const float* __restrict__ tau,
    float* __restrict__ out)
{
    __shared__ __align__(16) short Kb[2][4096];   // 16 KB dbuf (4 x 2KB slices)
    __shared__ __align__(16) short Vb[2][4096];   // 16 KB dbuf
    __shared__ __align__(16) short Qs[4096];      //  8 KB Q frags (qg*2+eb)*512+lane*8
    // total 40 KB -> 4 blocks/CU

    const int tid  = threadIdx.x;
    const int kq   = tid >> 6;        // wave id == key-quarter
    const int lane = tid & 63;
    const int ln   = lane & 15;
    const int quad = lane >> 4;

    const int bh = blockIdx.x;
    const int b  = bh >> 3, h = bh & 7;
    // co-resident {y,y+8,y+16,y+24} -> qt {31-2a, 2a, 30-2a, 2a+1}: 66 tiles/CU
    const int y = blockIdx.y, g8 = y >> 3, a = y & 7;
    const int qt = (g8 == 0) ? 31 - 2*a : (g8 == 1) ? 2*a
                 : (g8 == 2) ? 30 - 2*a : 2*a + 1;
    const int q0 = qt * 64;
    const int T  = qt + 1;            // 64-key tiles

    const float st2 = (0.125f * 1.44269504f) * tau[b];

    // per-wave incremental pointers (tile stride = 4096 shorts = 8 KB)
    const short* gK = Kf + (size_t)bh*(32*4096) + kq*1024 + lane*8;
    const short* gV = Vf + (size_t)bh*(32*4096) + kq*1024 + lane*8;
    const float* Dfp = Df + (size_t)b*Lsz + kq*16 + quad*4;

    // wave's private LDS slices
    short* const myK0 = &Kb[0][kq*1024];
    short* const myV0 = &Vb[0][kq*1024];

    // ---- stage tile 0 + Df(0): 4 stage16 + 1 dwordx4 = 5 VMEM ops/tile ----
#define STAGE(buf) do {                                                     \
        short* k_ = (buf) ? myK0 + 4096 : myK0;                             \
        short* v_ = (buf) ? myV0 + 4096 : myV0;                             \
        stage16(gK + 0*512, k_ + 0*512);                                    \
        stage16(gK + 1*512, k_ + 1*512);                                    \
        stage16(gV + 0*512, v_ + 0*512);                                    \
        stage16(gV + 1*512, v_ + 1*512);                                    \
        gK += 4096; gV += 4096;                                             \
        __builtin_amdgcn_sched_barrier(0);                                  \
    } while (0)
#define WAITN(n) do {                                                       \
        asm volatile("s_waitcnt vmcnt(" #n ")" ::: "memory");               \
        __builtin_amdgcn_sched_barrier(0);                                  \
    } while (0)

    STAGE(0);
    f32x4 dlv_c = *(const f32x4*)(Dfp); Dfp += 64;

    // ---- Q frags -> LDS (wave kq builds q-group qg=kq), one barrier ----
    {
        const float* qrow = q + (((size_t)b*Lsz + q0 + kq*16 + ln)*Hsz + h)*64;
        float4 a0 = *(const float4*)(qrow + quad*8);
        float4 a1 = *(const float4*)(qrow + quad*8 + 4);
        float4 b0 = *(const float4*)(qrow + 32 + quad*8);
        float4 b1 = *(const float4*)(qrow + 32 + quad*8 + 4);
        bf16x8 q0f = {f2bs(a0.x),f2bs(a0.y),f2bs(a0.z),f2bs(a0.w),
                      f2bs(a1.x),f2bs(a1.y),f2bs(a1.z),f2bs(a1.w)};
        bf16x8 q1f = {f2bs(b0.x),f2bs(b0.y),f2bs(b0.z),f2bs(b0.w),
                      f2bs(b1.x),f2bs(b1.y),f2bs(b1.z),f2bs(b1.w)};
        *(bf16x8*)(&Qs[(kq*2+0)*512 + lane*8]) = q0f;
        *(bf16x8*)(&Qs[(kq*2+1)*512 + lane*8]) = q1f;
    }

    f32x4 oacc[4][4];                 // [dg][qg]; O[q=qg*16+ln][d=dg*16+quad*4+i]
    #pragma unroll
    for (int dg = 0; dg < 4; ++dg)
        #pragma unroll
        for (int qg = 0; qg < 4; ++qg)
            oacc[dg][qg] = (f32x4){0.f,0.f,0.f,0.f};
    float l_acc[4] = {0.f,0.f,0.f,0.f};

    __syncthreads();                  // Q ready; tile 0 + Df(0) drained (once)

#define TILE_BODY(t_, MASKED, HASNEXT) do {                                 \
        const short* Kc_ = ((t_) & 1) ? myK0 + 4096 : myK0;                 \
        const short* Vc_ = ((t_) & 1) ? myV0 + 4096 : myV0;                 \
        f32x4 dlv_n_;                                                       \
        if (HASNEXT) {                                                      \
            STAGE(((t_)+1) & 1);                                            \
            dlv_n_ = *(const f32x4*)(Dfp); Dfp += 64;                       \
        }                                                                   \
        if (HASNEXT) WAITN(8); else WAITN(3);      /* K(t) resident */      \
        bf16x8 kf0_ = *(const bf16x8*)(Kc_ + 0*512 + lane*8);               \
        bf16x8 kf1_ = *(const bf16x8*)(Kc_ + 1*512 + lane*8);               \
        f32x4 sacc_[4];                                                     \
        __builtin_amdgcn_s_setprio(1);                                      \
        _Pragma("unroll")                                                   \
        for (int qg = 0; qg < 4; ++qg) {                                    \
            bf16x8 qa_ = *(const bf16x8*)(&Qs[(qg*2+0)*512 + lane*8]);      \
            bf16x8 qb_ = *(const bf16x8*)(&Qs[(qg*2+1)*512 + lane*8]);      \
            f32x4 z_ = (f32x4){0.f,0.f,0.f,0.f};                            \
            z_ = __builtin_amdgcn_mfma_f32_16x16x32_bf16(kf0_, qa_, z_, 0,0,0); \
            sacc_[qg] = __builtin_amdgcn_mfma_f32_16x16x32_bf16(kf1_, qb_, z_, 0,0,0); \
        }                                                                   \
        __builtin_amdgcn_s_setprio(0);                                      \
        if (MASKED) {                                                       \
            _Pragma("unroll")                                               \
            for (int qg = 0; qg < 4; ++qg)                                  \
                _Pragma("unroll")                                           \
                for (int r = 0; r < 4; ++r)                                 \
                    if (kq*16 + quad*4 + r > qg*16 + ln) sacc_[qg][r] = -1e30f; \
        }                                                                   \
        bf16x4 pT_[4];                                                      \
        _Pragma("unroll")                                                   \
        for (int qg = 0; qg < 4; ++qg) {                                    \
            float p0_ = __builtin_amdgcn_exp2f(fmaf(sacc_[qg][0], st2, dlv_c[0])); \
            float p1_ = __builtin_amdgcn_exp2f(fmaf(sacc_[qg][1], st2, dlv_c[1])); \
            float p2_ = __builtin_amdgcn_exp2f(fmaf(sacc_[qg][2], st2, dlv_c[2])); \
            float p3_ = __builtin_amdgcn_exp2f(fmaf(sacc_[qg][3], st2, dlv_c[3])); \
            l_acc[qg] += (p0_ + p1_) + (p2_ + p3_);                         \
            pT_[qg] = (bf16x4){f2bs_rh(p0_), f2bs_rh(p1_),                  \
                               f2bs_rh(p2_), f2bs_rh(p3_)};                 \
        }                                                                   \
        if (HASNEXT) dlv_c = dlv_n_;                                        \
        if (HASNEXT) WAITN(5); else WAITN(0);      /* V(t)+Df resident */   \
        bf16x4 vf_[4];                                                      \
        _Pragma("unroll")                                                   \
        for (int dg = 0; dg < 4; ++dg)                                      \
            vf_[dg] = *(const bf16x4*)(Vc_ + (dg>>1)*512 + lane*8 + (dg&1)*4); \
        __builtin_amdgcn_s_setprio(1);                                      \
        _Pragma("unroll")                                                   \
        for (int dg = 0; dg < 4; ++dg)                                      \
            _Pragma("unroll")                                               \
            for (int qg = 0; qg < 4; ++qg)                                  \
                oacc[dg][qg] = __builtin_amdgcn_mfma_f32_16x16x16bf16_1k(   \
                    vf_[dg], pT_[qg], oacc[dg][qg], 0,0,0);                 \
        __builtin_amdgcn_s_setprio(0);                                      \
    } while (0)

    // barrier-free main loop; diagonal (masked) tile last, no staging
    for (int t = 0; t < T - 1; ++t) TILE_BODY(t, false, true);
    TILE_BODY(T - 1, true, false);

    // ---- epilogue: 4-way cross-kq reduction of O and l via LDS overlays ----
    float lq[4];
    #pragma unroll
    for (int qg = 0; qg < 4; ++qg) {
        float s = l_acc[qg];
        s += __shfl_xor(s, 16, 64);
        s += __shfl_xor(s, 32, 64);
        lq[qg] = s;                   // full-wave l for (qg, q=ln), replicated
    }
    float* KbF = (float*)&Kb[0][0];   // 8 KB wave-1 O, layout (dg*4+qg)*256+lane*4
    float* VbF = (float*)&Vb[0][0];   // 8 KB wave-3 O   (f32x4 per lane slot)
    float* lred = (float*)&Qs[0];     // 256 f: [kq][qg][16 q]
    __syncthreads();                  // all loops done; Qs reads done

    if (lane < 16)
        #pragma unroll
        for (int qg = 0; qg < 4; ++qg) lred[kq*64 + qg*16 + ln] = lq[qg];
    if (kq == 1 || kq == 3) {
        float* dst = (kq == 1) ? KbF : VbF;
        #pragma unroll
        for (int dg = 0; dg < 4; ++dg)
            #pragma unroll
            for (int qg = 0; qg < 4; ++qg)
                *(f32x4*)(dst + (dg*4+qg)*256 + lane*4) = oacc[dg][qg];
    }
    __syncthreads();
    if (kq == 0 || kq == 2) {
        const float* srcp = (kq == 0) ? KbF : VbF;
        #pragma unroll
        for (int dg = 0; dg < 4; ++dg)
            #pragma unroll
            for (int qg = 0; qg < 4; ++qg) {
                f32x4 v = *(const f32x4*)(srcp + (dg*4+qg)*256 + lane*4);
                oacc[dg][qg][0] += v[0]; oacc[dg][qg][1] += v[1];
                oacc[dg][qg][2] += v[2]; oacc[dg][qg][3] += v[3];
            }
    }
    __syncthreads();
    if (kq == 2) {
        #pragma unroll
        for (int dg = 0; dg < 4; ++dg)
            #pragma unroll
            for (int qg = 0; qg < 4; ++qg)
                *(f32x4*)(KbF + (dg*4+qg)*256 + lane*4) = oacc[dg][qg];
    }
    __syncthreads();
    if (kq == 0) {
        float inv[4];
        #pragma unroll
        for (int qg = 0; qg < 4; ++qg)
            inv[qg] = 1.0f / (lred[qg*16 + ln] + lred[64 + qg*16 + ln]
                            + lred[128 + qg*16 + ln] + lred[192 + qg*16 + ln]);
        #pragma unroll
        for (int qg = 0; qg < 4; ++qg) {
            float* orow = out + (((size_t)b*Lsz + q0 + qg*16 + ln)*Hsz + h)*64;
            #pragma unroll
            for (int dg = 0; dg < 4; ++dg) {
                f32x4 v = *(const f32x4*)(KbF + (dg*4+qg)*256 + lane*4);
                float4 o = {(oacc[dg][qg][0] + v[0]) * inv[qg],
                            (oacc[dg][qg][1] + v[1]) * inv[qg],
                            (oacc[dg][qg][2] + v[2]) * inv[qg],
                            (oacc[dg][qg][3] + v[3]) * inv[qg]};
                *(float4*)(orow + dg*16 + quad*4) = o;
            }
        }
    }
#undef STAGE
#undef WAITN
#undef TILE_BODY
}

extern "C" void kernel_launch(void* const* d_in, const int* in_sizes, int n_in,
                              void* d_out, int out_size, void* d_ws, size_t ws_size,
                              hipStream_t stream) {
    (void)in_sizes; (void)n_in; (void)out_size; (void)ws_size;
    const float* q     = (const float*)d_in[0];
    const float* k     = (const float*)d_in[1];
    const float* v     = (const float*)d_in[2];
    const float* tau   = (const float*)d_in[3];
    const float* delta = (const float*)d_in[4];
    float* out = (float*)d_out;

    short* Kf = (short*)d_ws;                          // 8 MiB bf16 fragments
    short* Vf = (short*)d_ws + (size_t)(4*1024*1024);  // next 8 MiB
    float* Df = (float*)((char*)d_ws + (size_t)(16*1024*1024)); // 32 KB c2*delta

    prep_kv<<<dim3(Bsz*Hsz*32*2 + 2), dim3(256), 0, stream>>>(k, v, delta, Kf, Vf, Df);
    dsattn_main<<<dim3(Bsz*Hsz, 32), dim3(256), 0, stream>>>(q, Kf, Vf, Df, tau, out);
}